// Round 8
// baseline (499.425 us; speedup 1.0000x reference)
//
#include <hip/hip_runtime.h>
#include <math.h>

#define BB 2048          // batch
#define FD 256           // num_features
#define HD 128           // hidden
#define FF 65536         // F*F
#define TK 15            // top-k
#define BCAP 1024        // per-block candidate list cap (k2)
#define MAXCH 4          // max 64-candidate chunks in k3 (capr<=256)
#define POISON (1 << 30) // row poison flag in gcnt -> k3 exact fallback
#define NEG_INF (-3.4e38f)
#define EPSF 1e-8f
#define ZCLAMP 1.4f

typedef short short8 __attribute__((ext_vector_type(8)));   // 8 bf16 (4 VGPRs)
typedef float f32x4  __attribute__((ext_vector_type(4)));

__device__ __forceinline__ unsigned short bf16_rne(float x) {
  unsigned u = __float_as_uint(x);
  unsigned r = u + 0x7FFFu + ((u >> 16) & 1u);
  return (unsigned short)(r >> 16);
}

// Taylor of h(z) = -sigma(z)*ln(sigma(z)) about 0 (err<=4.2e-5 at |z|=1,
// ~9e-4 at 1.4; values with |z|>1.4 get the exact rare-path correction).
#define HC0 3.4657359e-01f
#define HC1 (-7.6713203e-02f)
#define HC2 (-6.25e-02f)
#define HC3 1.6809444e-02f
#define HC4 7.8125e-03f
#define HC5 (-2.4621900e-03f)
#define HC6 (-8.6805556e-04f)
#define HC7 3.0960500e-04f
#define HC8 9.2231000e-05f

__device__ __forceinline__ float hpoly(float zc) {
  float p = HC8;
  p = fmaf(p, zc, HC7); p = fmaf(p, zc, HC6); p = fmaf(p, zc, HC5);
  p = fmaf(p, zc, HC4); p = fmaf(p, zc, HC3); p = fmaf(p, zc, HC2);
  p = fmaf(p, zc, HC1); p = fmaf(p, zc, HC0);
  return p;
}

// ---------------------------------------------------------------------------
// Kernel 1: front-end MLPs + fused per-row tau (1024 exact sample logits,
// tau = mu + 3.1*sd). Writes hrs, hb (bf16), tf, opw, tau; zeroes gcnt.
// (R7-verified)
// ---------------------------------------------------------------------------
__global__ __launch_bounds__(256) void k1_front(
    const float* __restrict__ x,
    const float* __restrict__ rs_w1, const float* __restrict__ rs_b1,
    const float* __restrict__ rs_w2, const float* __restrict__ rs_b2,
    const float* __restrict__ os_w1, const float* __restrict__ os_b1,
    const float* __restrict__ os_w2, const float* __restrict__ os_b2,
    const float* __restrict__ ft_w1, const float* __restrict__ ft_b1,
    const float* __restrict__ ft_w2, const float* __restrict__ ft_b2,
    float* __restrict__ hrs, unsigned short* __restrict__ hb,
    float* __restrict__ tf, float* __restrict__ opw,
    float* __restrict__ tau, int* __restrict__ gcnt)
{
  __shared__ float xs[4 * FD];
  __shared__ float hft[4][HD];
  __shared__ float hos[4][HD];
  __shared__ float hl[4 * HD];
  __shared__ float lg[4][4];
  __shared__ float wred[4][4][2];
  const int tid = threadIdx.x;
  const int wave = tid >> 6, lane = tid & 63;
  const int r0  = blockIdx.x * 4;

  if (tid < 4) gcnt[blockIdx.x * 4 + tid] = 0;

  for (int i = tid; i < 4 * FD; i += 256) xs[i] = x[(size_t)r0 * FD + i];
  __syncthreads();

  {
    const int h    = tid & (HD - 1);
    const int half = tid >> 7;
    const int ra = 2 * half, rb = ra + 1;
    float a0=0.f,a1=0.f,b0=0.f,b1=0.f,c0=0.f,c1=0.f;
    for (int f = 0; f < FD; ++f) {
      const float wr = rs_w1[f*HD+h], wf = ft_w1[f*HD+h], wo = os_w1[f*HD+h];
      const float x0 = xs[ra*FD+f],   x1 = xs[rb*FD+f];
      a0 = fmaf(x0,wr,a0); a1 = fmaf(x1,wr,a1);
      b0 = fmaf(x0,wf,b0); b1 = fmaf(x1,wf,b1);
      c0 = fmaf(x0,wo,c0); c1 = fmaf(x1,wo,c1);
    }
    const float brs = rs_b1[h], bft = ft_b1[h], bos = os_b1[h];
    const float va = fmaxf(a0 + brs, 0.f), vb = fmaxf(a1 + brs, 0.f);
    hrs[(size_t)(r0+ra)*HD + h] = va;
    hrs[(size_t)(r0+rb)*HD + h] = vb;
    hb[(size_t)(r0+ra)*HD + h] = bf16_rne(va);
    hb[(size_t)(r0+rb)*HD + h] = bf16_rne(vb);
    hl[ra*HD + h] = va;
    hl[rb*HD + h] = vb;
    hft[ra][h] = fmaxf(b0 + bft, 0.f);
    hft[rb][h] = fmaxf(b1 + bft, 0.f);
    hos[ra][h] = fmaxf(c0 + bos, 0.f);
    hos[rb][h] = fmaxf(c1 + bos, 0.f);
  }
  __syncthreads();

  {
    const int c = tid;
    const float bb = ft_b2[c];
    float t0=bb,t1=bb,t2=bb,t3=bb;
    for (int h = 0; h < HD; ++h) {
      const float w = ft_w2[h*FD + c];
      t0 = fmaf(hft[0][h],w,t0); t1 = fmaf(hft[1][h],w,t1);
      t2 = fmaf(hft[2][h],w,t2); t3 = fmaf(hft[3][h],w,t3);
    }
    tf[(size_t)(r0+0)*FD+c]=t0; tf[(size_t)(r0+1)*FD+c]=t1;
    tf[(size_t)(r0+2)*FD+c]=t2; tf[(size_t)(r0+3)*FD+c]=t3;
  }

  if (tid < 16) {
    const int r = tid >> 2, o = tid & 3;
    float a = os_b2[o];
    for (int h = 0; h < HD; ++h) a = fmaf(hos[r][h], os_w2[h*4 + o], a);
    lg[r][o] = a;
  }
  __syncthreads();
  if (tid < 16) {
    const int r = tid >> 2, o = tid & 3;
    const float m = fmaxf(fmaxf(lg[r][0],lg[r][1]), fmaxf(lg[r][2],lg[r][3]));
    const float e = __expf(lg[r][o]-m);
    const float s = __expf(lg[r][0]-m)+__expf(lg[r][1]-m)+__expf(lg[r][2]-m)+__expf(lg[r][3]-m);
    opw[(size_t)(r0+r)*4+o] = e/s;
  }

  // fused tau phase: 1024 sample logits from cols 0..1023
  {
    const int c0 = tid * 4;
    float z[4][4];
    const float4 bb = *(const float4*)(rs_b2 + c0);
#pragma unroll
    for (int r = 0; r < 4; ++r) { z[r][0]=bb.x; z[r][1]=bb.y; z[r][2]=bb.z; z[r][3]=bb.w; }
    for (int k = 0; k < HD; ++k) {
      const float4 ww = *(const float4*)(rs_w2 + (size_t)k * FF + c0);
#pragma unroll
      for (int r = 0; r < 4; ++r) {
        const float a = hl[r * HD + k];
        z[r][0] = fmaf(a, ww.x, z[r][0]);
        z[r][1] = fmaf(a, ww.y, z[r][1]);
        z[r][2] = fmaf(a, ww.z, z[r][2]);
        z[r][3] = fmaf(a, ww.w, z[r][3]);
      }
    }
#pragma unroll
    for (int r = 0; r < 4; ++r) {
      float s1 = z[r][0] + z[r][1] + z[r][2] + z[r][3];
      float s2 = z[r][0]*z[r][0] + z[r][1]*z[r][1] + z[r][2]*z[r][2] + z[r][3]*z[r][3];
#pragma unroll
      for (int d = 1; d < 64; d <<= 1) { s1 += __shfl_xor(s1, d); s2 += __shfl_xor(s2, d); }
      if (lane == 0) { wred[wave][r][0] = s1; wred[wave][r][1] = s2; }
    }
    __syncthreads();
    if (tid < 4) {
      const float s1 = wred[0][tid][0]+wred[1][tid][0]+wred[2][tid][0]+wred[3][tid][0];
      const float s2 = wred[0][tid][1]+wred[1][tid][1]+wred[2][tid][1]+wred[3][tid][1];
      const float mu  = s1 * (1.f / 1024.f);
      const float var = fmaxf(s2 * (1.f / 1024.f) - mu * mu, 0.f);
      const float sd  = sqrtf(var);
      tau[r0 + tid] = (sd > 1e-6f * (fabsf(mu) + 1e-6f)) ? (mu + 3.1f * sd) : NEG_INF;
    }
  }
}

// ---------------------------------------------------------------------------
// Kernel 2: bf16 MFMA GEMM, 128 cols x 512 rows per block.
// R8: B-frags in LDS (frees 64 VGPRs -> launch_bounds(256,4), 4 waves/SIMD);
// branchless clamp-poly entropy with per-mt __any exact correction; grid
// swizzle so a col-chunk's 4 row-splits are consecutive on one XCD (W2 L2
// reuse). Survivors exactly recomputed in fp32 into per-row global lists.
// ---------------------------------------------------------------------------
__global__ __launch_bounds__(256, 4) void k2_sel(
    const float* __restrict__ W2, const float* __restrict__ b2,
    const float* __restrict__ hrs, const unsigned short* __restrict__ hb,
    const float* __restrict__ tau,
    int* __restrict__ gcnt, float* __restrict__ gz, int* __restrict__ gi,
    float* __restrict__ ent_part, int capr)
{
  __shared__ uint4 Blds[2][16][64];   // [col-half][ct*4+ks][lane]  32 KB
  __shared__ int   cands[BCAP];       // 4 KB
  __shared__ float tau_l[512];        // 2 KB
  __shared__ int   bcnt;
  __shared__ float entred[4];

  const int tid  = threadIdx.x;
  const int wave = tid >> 6, lane = tid & 63;
  const int n16  = lane & 15, quad = lane >> 4;
  // swizzle: XCD = bx%8; in-XCD order j; 4 consecutive j share col-chunk cc
  const int xcd = blockIdx.x & 7, jj = blockIdx.x >> 3;
  const int cc  = ((jj >> 2) << 3) | xcd, rs = jj & 3;
  const int c0  = cc * 128, rbase = rs * 512;
  const int half = wave & 1, wrow0 = (wave >> 1) * 64;
  const int wcol0 = half * 64;

  if (tid == 0) bcnt = 0;
  tau_l[tid] = tau[rbase + tid];
  tau_l[tid + 256] = tau[rbase + 256 + tid];

  // stage B: fp32 W2 -> bf16 fragments in LDS (2048 uint4, 8 per thread)
  for (int p = 0; p < 8; ++p) {
    const int pid = p * 256 + tid;
    const int bh = pid >> 10;
    const int rest = pid & 1023;
    const int bct = rest >> 8, bks = (rest >> 6) & 3, bln = rest & 63;
    const int bn16 = bln & 15, bqd = bln >> 4;
    const int col = c0 + bh * 64 + bct * 16 + bn16;
    const int k0 = bks * 32 + bqd * 8;
    short8 f;
#pragma unroll
    for (int u = 0; u < 8; ++u)
      f[u] = (short)bf16_rne(W2[(size_t)(k0 + u) * FF + col]);
    Blds[bh][bct * 4 + bks][bln] = __builtin_bit_cast(uint4, f);
  }
  __syncthreads();

  float bv[4];
#pragma unroll
  for (int ct = 0; ct < 4; ++ct) bv[ct] = b2[c0 + wcol0 + ct * 16 + n16];

  float ent = 0.f;

  for (int mt = 0; mt < 4; ++mt) {
    const int mrow = rbase + mt * 128 + wrow0;   // this wave's 64-row band

    f32x4 acc[4][4];
#pragma unroll
    for (int rt = 0; rt < 4; ++rt)
#pragma unroll
      for (int ct = 0; ct < 4; ++ct) acc[rt][ct] = (f32x4){0.f, 0.f, 0.f, 0.f};

#pragma unroll
    for (int ks = 0; ks < 4; ++ks) {
      short8 af[4], bfr[4];
#pragma unroll
      for (int rt = 0; rt < 4; ++rt)
        af[rt] = __builtin_bit_cast(short8,
            *(const uint4*)(hb + (size_t)(mrow + rt * 16 + n16) * HD + ks * 32 + quad * 8));
#pragma unroll
      for (int ct = 0; ct < 4; ++ct)
        bfr[ct] = __builtin_bit_cast(short8, Blds[half][ct * 4 + ks][lane]);
#pragma unroll
      for (int rt = 0; rt < 4; ++rt)
#pragma unroll
        for (int ct = 0; ct < 4; ++ct)
          acc[rt][ct] = __builtin_amdgcn_mfma_f32_16x16x32_bf16(
              af[rt], bfr[ct], acc[rt][ct], 0, 0, 0);
    }

    // branchless entropy (clamped poly) + __any-guarded filter
    float zmax = 0.f;
#pragma unroll
    for (int rt = 0; rt < 4; ++rt) {
      const int rl0 = mt * 128 + wrow0 + rt * 16 + quad * 4;   // block-local row
      const f32x4 tl = *(const f32x4*)&tau_l[rl0];
#pragma unroll
      for (int ct = 0; ct < 4; ++ct) {
#pragma unroll
        for (int rg = 0; rg < 4; ++rg) {
          const float z = acc[rt][ct][rg] + bv[ct];
          zmax = fmaxf(zmax, __builtin_fabsf(z));
          const float zc = fminf(fmaxf(z, -ZCLAMP), ZCLAMP);
          ent -= hpoly(zc);
          if (__any(z >= tl[rg])) {
            if (z >= tl[rg]) {
              const int q  = atomicAdd(&bcnt, 1);
              const int gm = rl0 + rg;
              if (q < BCAP) cands[q] = (gm << 7) | (wcol0 + ct * 16 + n16);
              else atomicOr(&gcnt[rbase + gm], POISON);
            }
          }
        }
      }
    }
    if (__any(zmax > ZCLAMP)) {   // rare exact correction for clamped values
#pragma unroll
      for (int rt = 0; rt < 4; ++rt)
#pragma unroll
        for (int ct = 0; ct < 4; ++ct)
#pragma unroll
          for (int rg = 0; rg < 4; ++rg) {
            const float z = acc[rt][ct][rg] + bv[ct];
            if (__builtin_fabsf(z) > ZCLAMP) {
              const float zc = fminf(fmaxf(z, -ZCLAMP), ZCLAMP);
              const float zx = fmaxf(z, -60.f);
              const float w = 1.f + __expf(-zx);
              ent += hpoly(zc) - __logf(w) * __builtin_amdgcn_rcpf(w);
            }
          }
    }
  }

  __syncthreads();
  // exact fp32 recompute of candidates: one 16-lane group per candidate
  {
    const int nc = min(bcnt, BCAP);
    const int grp = tid >> 4, gl = tid & 15;
    for (int ci = grp; ci < nc; ci += 16) {
      const int pk = cands[ci];
      const int r = rbase + (pk >> 7), c = c0 + (pk & 127);
      float s = 0.f;
      const int k0 = gl * 8;
#pragma unroll
      for (int u = 0; u < 8; ++u)
        s = fmaf(hrs[(size_t)r * HD + k0 + u], W2[(size_t)(k0 + u) * FF + c], s);
#pragma unroll
      for (int d = 1; d < 16; d <<= 1) s += __shfl_xor(s, d);
      if (gl == 0) {
        const float z = s + b2[c];
        const int pos = atomicAdd(&gcnt[r], 1);
        if (pos < capr) {
          gz[(size_t)r * capr + pos] = z;
          gi[(size_t)r * capr + pos] = c;
        }
      }
    }
  }

  // entropy reduce -> one partial per block
#pragma unroll
  for (int off = 32; off >= 1; off >>= 1) ent += __shfl_down(ent, off);
  if (lane == 0) entred[wave] = ent;
  __syncthreads();
  if (tid == 0) ent_part[blockIdx.x] = entred[0] + entred[1] + entred[2] + entred[3];
}

// ---------------------------------------------------------------------------
// Kernel 3: per-row selection (R4-R7-verified). Fast path: count in [15,capr]
// AND exact-15th >= sigmoid(tau) certificate; else block-cooperative exact
// full-row scan (~never).
// ---------------------------------------------------------------------------
__global__ __launch_bounds__(256) void k3_select(
    const int* __restrict__ gcnt, const float* __restrict__ gz, const int* __restrict__ gi,
    const float* __restrict__ tau,
    const float* __restrict__ hrs, const float* __restrict__ W2, const float* __restrict__ b2,
    const float* __restrict__ tf, const float* __restrict__ opw,
    float* __restrict__ out_rt, float* __restrict__ pi_part, float* __restrict__ mag_part,
    int capr)
{
  __shared__ float csv[4][MAXCH][16];
  __shared__ int   csi[4][MAXCH][16];
  __shared__ float tv[4][TK];
  __shared__ int   ti[4][TK];
  __shared__ float s_pi[4][TK];
  __shared__ float s_mag[4][TK];
  __shared__ float red_v[256];
  __shared__ int   red_i[256];
  __shared__ float hrow[HD];
  __shared__ int   fb_w[4];
  __shared__ int   fb_n;

  const int tid  = threadIdx.x;
  const int wave = tid >> 6, lane = tid & 63;
  const int row  = blockIdx.x * 4 + wave;
  if (tid == 0) fb_n = 0;
  __syncthreads();

  const int raw = gcnt[row];
  const float tau_r = tau[row];
  int okflag = (raw >= TK && raw <= capr) ? 1 : 0;

  if (okflag) {
    const int nch = (raw + 63) >> 6;   // <= MAXCH
    for (int ch = 0; ch < nch; ++ch) {
      const int sl = ch * 64 + lane;
      float v; int ix;
      if (sl < raw) {
        const float z = gz[(size_t)row * capr + sl];
        v  = 1.f / (1.f + __expf(-z));
        ix = gi[(size_t)row * capr + sl];
      } else { v = -1.f; ix = 0x7fffffff; }
#pragma unroll
      for (int k = 2; k <= 64; k <<= 1) {
#pragma unroll
        for (int j = k >> 1; j >= 1; j >>= 1) {
          const float pv = __shfl_xor(v, j);
          const int   pj = __shfl_xor(ix, j);
          const bool up    = ((lane & k) == 0);
          const bool lower = ((lane & j) == 0);
          const bool gt = (v > pv) || (v == pv && ix < pj);
          const bool keep = (lower == up) ? gt : !gt;
          if (!keep) { v = pv; ix = pj; }
        }
      }
      if (lane < 16) { csv[wave][ch][lane] = v; csi[wave][ch][lane] = ix; }
    }
    if (lane == 0) {
      int p[MAXCH];
#pragma unroll
      for (int i = 0; i < MAXCH; ++i) p[i] = 0;
      for (int round = 0; round < TK; ++round) {
        float bvv = -2.f; int bi = 0x7fffffff; int bw = 0;
        for (int ch = 0; ch < nch; ++ch) {
          if (p[ch] < 16) {
            const float vv = csv[wave][ch][p[ch]];
            const int   ii = csi[wave][ch][p[ch]];
            if (vv > bvv || (vv == bvv && ii < bi)) { bvv = vv; bi = ii; bw = ch; }
          }
        }
        ++p[bw];
        tv[wave][round] = bvv; ti[wave][round] = bi;
      }
      const float stau = 1.f / (1.f + __expf(-tau_r));
      if (tv[wave][TK - 1] < stau) okflag = 0;   // certificate
    }
    okflag = __shfl(okflag, 0);
  }
  if (!okflag && lane == 0) { const int q = atomicAdd(&fb_n, 1); fb_w[q] = wave; }
  __syncthreads();

  const int nfb = fb_n;
  for (int f = 0; f < nfb; ++f) {
    const int w = fb_w[f];
    const int frow = blockIdx.x * 4 + w;
    for (int i = tid; i < HD; i += 256) hrow[i] = hrs[(size_t)frow * HD + i];
    __syncthreads();
    float kv[TK]; int ki[TK];
#pragma unroll
    for (int q = 0; q < TK; ++q) { kv[q] = -2.f; ki[q] = 0x7fffffff; }
    for (int u = 0; u < FF / 256; ++u) {
      const int c = u * 256 + tid;
      float z = b2[c];
      for (int k = 0; k < HD; ++k) z = fmaf(hrow[k], W2[(size_t)k * FF + c], z);
      const float s = 1.f / (1.f + __expf(-z));
      if (s > kv[TK-1] || (s == kv[TK-1] && c < ki[TK-1])) {
        float cv = s; int cc2 = c;
#pragma unroll
        for (int q = 0; q < TK; ++q) {
          const bool bet = (cv > kv[q]) || (cv == kv[q] && cc2 < ki[q]);
          const float tq = kv[q]; const int tj = ki[q];
          if (bet) { kv[q] = cv; ki[q] = cc2; cv = tq; cc2 = tj; }
        }
      }
    }
    int pi = 0;
    for (int round = 0; round < TK; ++round) {
      red_v[tid] = (pi < TK) ? kv[pi] : -2.f;
      red_i[tid] = (pi < TK) ? ki[pi] : 0x7fffffff;
      __syncthreads();
      for (int off = 128; off >= 1; off >>= 1) {
        if (tid < off) {
          const float ov = red_v[tid + off]; const int oi = red_i[tid + off];
          if (ov > red_v[tid] || (ov == red_v[tid] && oi < red_i[tid])) {
            red_v[tid] = ov; red_i[tid] = oi;
          }
        }
        __syncthreads();
      }
      const float wv = red_v[0]; const int wi = red_i[0];
      __syncthreads();
      if (pi < TK && ki[pi] == wi) ++pi;
      if (tid == 0) { tv[w][round] = wv; ti[w][round] = wi; }
    }
    __syncthreads();
  }
  __syncthreads();

  if (lane < TK) {
    const float rv = tv[wave][lane];
    const int j = ti[wave][lane], ii = j >> 8, jj = j & 255;
    const float fi = tf[(size_t)row * FD + ii];
    const float fj = tf[(size_t)row * FD + jj];
    const float* w = opw + (size_t)row * 4;
    const float ratio = fi / (fabsf(fj) + EPSF);
    const float lr    = logf(fabsf(fi) + EPSF) - logf(fabsf(fj) + EPSF);
    const float rt    = ratio * w[0] + lr * w[1] + (fi - fj) * w[2] + fi * fj * w[3];
    out_rt[(size_t)row * TK + lane] = rt;
    s_pi[wave][lane]  = rv;
    s_mag[wave][lane] = fabsf(rt);
  }
  __syncthreads();
  if (tid < TK) {
    pi_part[(size_t)blockIdx.x * TK + tid]  = s_pi[0][tid]+s_pi[1][tid]+s_pi[2][tid]+s_pi[3][tid];
    mag_part[(size_t)blockIdx.x * TK + tid] = s_mag[0][tid]+s_mag[1][tid]+s_mag[2][tid]+s_mag[3][tid];
  }
}

// ---------------------------------------------------------------------------
// Kernel 4: final reductions, 4 independent sections -> 4 blocks.
// ---------------------------------------------------------------------------
__global__ __launch_bounds__(256) void k4_final(
    const float* __restrict__ pi_part, const float* __restrict__ mag_part,
    const float* __restrict__ opw, const float* __restrict__ ent_part,
    float* __restrict__ out)
{
  __shared__ float red[256];
  const int tid = threadIdx.x;
  const int NB3 = BB / 4;          // 512
  const int base = BB * TK;        // 30720
  const int sec = blockIdx.x;

  if (sec == 0) {
    const int r = tid & 15, seg = tid >> 4;
    float s = 0.f;
    if (r < TK) for (int q = seg; q < NB3; q += 16) s += pi_part[(size_t)q * TK + r];
    red[tid] = s; __syncthreads();
    if (tid < TK) { float t = 0.f; for (int g = 0; g < 16; ++g) t += red[g*16 + tid];
      out[base + tid] = t / (float)BB; }
  } else if (sec == 1) {
    const int r = tid & 15, seg = tid >> 4;
    float s = 0.f;
    if (r < TK) for (int q = seg; q < NB3; q += 16) s += mag_part[(size_t)q * TK + r];
    red[tid] = s; __syncthreads();
    if (tid < TK) { float t = 0.f; for (int g = 0; g < 16; ++g) t += red[g*16 + tid];
      out[base + 19 + tid] = t / (float)BB; }
  } else if (sec == 2) {
    const int o = tid & 3, seg = tid >> 2;
    float s = 0.f;
    for (int q = seg; q < BB; q += 64) s += opw[(size_t)q * 4 + o];
    red[tid] = s; __syncthreads();
    if (tid < 4) { float t = 0.f; for (int g = 0; g < 64; ++g) t += red[g*4 + tid];
      out[base + 15 + tid] = t / (float)BB; }
  } else {
    float s = 0.f;
    for (int q = tid; q < 2048; q += 256) s += ent_part[q];
    red[tid] = s; __syncthreads();
    for (int off = 128; off >= 1; off >>= 1) {
      if (tid < off) red[tid] += red[tid + off];
      __syncthreads();
    }
    if (tid == 0) out[base + 34] = -red[0] / (float)BB;
  }
}

// ---------------------------------------------------------------------------
extern "C" void kernel_launch(void* const* d_in, const int* in_sizes, int n_in,
                              void* d_out, int out_size, void* d_ws, size_t ws_size,
                              hipStream_t stream) {
  (void)in_sizes; (void)n_in; (void)out_size;
  const float* x     = (const float*)d_in[0];
  const float* rs_w1 = (const float*)d_in[1];
  const float* rs_b1 = (const float*)d_in[2];
  const float* rs_w2 = (const float*)d_in[3];
  const float* rs_b2 = (const float*)d_in[4];
  const float* os_w1 = (const float*)d_in[5];
  const float* os_b1 = (const float*)d_in[6];
  const float* os_w2 = (const float*)d_in[7];
  const float* os_b2 = (const float*)d_in[8];
  const float* ft_w1 = (const float*)d_in[9];
  const float* ft_b1 = (const float*)d_in[10];
  const float* ft_w2 = (const float*)d_in[11];
  const float* ft_b2 = (const float*)d_in[12];
  float* out = (float*)d_out;

  float* ws       = (float*)d_ws;
  float* hrs      = ws;                                 // 2048*128 f32
  float* tf       = hrs + (size_t)BB * HD;              // 2048*256 f32
  float* opw      = tf + (size_t)BB * FD;               // 2048*4 f32
  float* ent_part = opw + (size_t)BB * 4;               // 2048 f32 (k2 blocks)
  float* pi_part  = ent_part + 2048;                    // 512*15 f32
  float* mag_part = pi_part + 512 * TK;                 // 512*15 f32
  float* tau      = mag_part + 512 * TK;                // 2048 f32
  unsigned short* hb = (unsigned short*)(tau + BB);     // 2048*128 bf16
  int*   gcnt     = (int*)(hb + (size_t)BB * HD);       // 2048 int
  float* gz       = (float*)(gcnt + BB);                // 2048*capr f32
  const size_t fixed = (size_t)((char*)gz - (char*)d_ws);
  int capr = 64 * MAXCH;                                // 256 target
  while (capr > 64 && fixed + (size_t)BB * capr * 8 > ws_size) capr -= 64;
  int* gi = (int*)(gz + (size_t)BB * capr);

  hipLaunchKernelGGL(k1_front, dim3(BB / 4), dim3(256), 0, stream,
                     x, rs_w1, rs_b1, rs_w2, rs_b2, os_w1, os_b1, os_w2, os_b2,
                     ft_w1, ft_b1, ft_w2, ft_b2, hrs, hb, tf, opw, tau, gcnt);
  hipLaunchKernelGGL(k2_sel, dim3(512 * 4), dim3(256), 0, stream,
                     rs_w2, rs_b2, hrs, hb, tau, gcnt, gz, gi, ent_part, capr);
  hipLaunchKernelGGL(k3_select, dim3(BB / 4), dim3(256), 0, stream,
                     gcnt, gz, gi, tau, hrs, rs_w2, rs_b2, tf, opw,
                     out, pi_part, mag_part, capr);
  hipLaunchKernelGGL(k4_final, dim3(4), dim3(256), 0, stream,
                     pi_part, mag_part, opw, ent_part, out);
}

// Round 9
// 292.048 us; speedup vs baseline: 1.7101x; 1.7101x over previous
//
#include <hip/hip_runtime.h>
#include <math.h>

#define BB 2048          // batch
#define FD 256           // num_features
#define HD 128           // hidden
#define FF 65536         // F*F
#define TK 15            // top-k
#define BCAP 1024        // per-block candidate list cap (k2)
#define MAXCH 4          // max 64-candidate chunks in k3 (capr<=256)
#define POISON (1 << 30) // row poison flag in gcnt -> k3 exact fallback
#define NEG_INF (-3.4e38f)
#define EPSF 1e-8f
#define ZCLAMP 1.4f

typedef short short8 __attribute__((ext_vector_type(8)));   // 8 bf16 (4 VGPRs)
typedef float f32x4  __attribute__((ext_vector_type(4)));

__device__ __forceinline__ unsigned short bf16_rne(float x) {
  unsigned u = __float_as_uint(x);
  unsigned r = u + 0x7FFFu + ((u >> 16) & 1u);
  return (unsigned short)(r >> 16);
}

// Taylor of h(z) = -sigma(z)*ln(sigma(z)) about 0 (err<=4.2e-5 at |z|=1,
// ~9e-4 at 1.4; |z|>1.4 gets the exact rare-path correction).
#define HC0 3.4657359e-01f
#define HC1 (-7.6713203e-02f)
#define HC2 (-6.25e-02f)
#define HC3 1.6809444e-02f
#define HC4 7.8125e-03f
#define HC5 (-2.4621900e-03f)
#define HC6 (-8.6805556e-04f)
#define HC7 3.0960500e-04f
#define HC8 9.2231000e-05f

__device__ __forceinline__ float hpoly(float zc) {
  float p = HC8;
  p = fmaf(p, zc, HC7); p = fmaf(p, zc, HC6); p = fmaf(p, zc, HC5);
  p = fmaf(p, zc, HC4); p = fmaf(p, zc, HC3); p = fmaf(p, zc, HC2);
  p = fmaf(p, zc, HC1); p = fmaf(p, zc, HC0);
  return p;
}

// ---------------------------------------------------------------------------
// Kernel 1: front-end MLPs + fused per-row tau (1024 exact sample logits,
// tau = mu + 3.1*sd). Writes hrs, hb (bf16), tf, opw, tau; zeroes gcnt.
// (R7/R8-verified)
// ---------------------------------------------------------------------------
__global__ __launch_bounds__(256) void k1_front(
    const float* __restrict__ x,
    const float* __restrict__ rs_w1, const float* __restrict__ rs_b1,
    const float* __restrict__ rs_w2, const float* __restrict__ rs_b2,
    const float* __restrict__ os_w1, const float* __restrict__ os_b1,
    const float* __restrict__ os_w2, const float* __restrict__ os_b2,
    const float* __restrict__ ft_w1, const float* __restrict__ ft_b1,
    const float* __restrict__ ft_w2, const float* __restrict__ ft_b2,
    float* __restrict__ hrs, unsigned short* __restrict__ hb,
    float* __restrict__ tf, float* __restrict__ opw,
    float* __restrict__ tau, int* __restrict__ gcnt)
{
  __shared__ float xs[4 * FD];
  __shared__ float hft[4][HD];
  __shared__ float hos[4][HD];
  __shared__ float hl[4 * HD];
  __shared__ float lg[4][4];
  __shared__ float wred[4][4][2];
  const int tid = threadIdx.x;
  const int wave = tid >> 6, lane = tid & 63;
  const int r0  = blockIdx.x * 4;

  if (tid < 4) gcnt[blockIdx.x * 4 + tid] = 0;

  for (int i = tid; i < 4 * FD; i += 256) xs[i] = x[(size_t)r0 * FD + i];
  __syncthreads();

  {
    const int h    = tid & (HD - 1);
    const int half = tid >> 7;
    const int ra = 2 * half, rb = ra + 1;
    float a0=0.f,a1=0.f,b0=0.f,b1=0.f,c0=0.f,c1=0.f;
    for (int f = 0; f < FD; ++f) {
      const float wr = rs_w1[f*HD+h], wf = ft_w1[f*HD+h], wo = os_w1[f*HD+h];
      const float x0 = xs[ra*FD+f],   x1 = xs[rb*FD+f];
      a0 = fmaf(x0,wr,a0); a1 = fmaf(x1,wr,a1);
      b0 = fmaf(x0,wf,b0); b1 = fmaf(x1,wf,b1);
      c0 = fmaf(x0,wo,c0); c1 = fmaf(x1,wo,c1);
    }
    const float brs = rs_b1[h], bft = ft_b1[h], bos = os_b1[h];
    const float va = fmaxf(a0 + brs, 0.f), vb = fmaxf(a1 + brs, 0.f);
    hrs[(size_t)(r0+ra)*HD + h] = va;
    hrs[(size_t)(r0+rb)*HD + h] = vb;
    hb[(size_t)(r0+ra)*HD + h] = bf16_rne(va);
    hb[(size_t)(r0+rb)*HD + h] = bf16_rne(vb);
    hl[ra*HD + h] = va;
    hl[rb*HD + h] = vb;
    hft[ra][h] = fmaxf(b0 + bft, 0.f);
    hft[rb][h] = fmaxf(b1 + bft, 0.f);
    hos[ra][h] = fmaxf(c0 + bos, 0.f);
    hos[rb][h] = fmaxf(c1 + bos, 0.f);
  }
  __syncthreads();

  {
    const int c = tid;
    const float bb = ft_b2[c];
    float t0=bb,t1=bb,t2=bb,t3=bb;
    for (int h = 0; h < HD; ++h) {
      const float w = ft_w2[h*FD + c];
      t0 = fmaf(hft[0][h],w,t0); t1 = fmaf(hft[1][h],w,t1);
      t2 = fmaf(hft[2][h],w,t2); t3 = fmaf(hft[3][h],w,t3);
    }
    tf[(size_t)(r0+0)*FD+c]=t0; tf[(size_t)(r0+1)*FD+c]=t1;
    tf[(size_t)(r0+2)*FD+c]=t2; tf[(size_t)(r0+3)*FD+c]=t3;
  }

  if (tid < 16) {
    const int r = tid >> 2, o = tid & 3;
    float a = os_b2[o];
    for (int h = 0; h < HD; ++h) a = fmaf(hos[r][h], os_w2[h*4 + o], a);
    lg[r][o] = a;
  }
  __syncthreads();
  if (tid < 16) {
    const int r = tid >> 2, o = tid & 3;
    const float m = fmaxf(fmaxf(lg[r][0],lg[r][1]), fmaxf(lg[r][2],lg[r][3]));
    const float e = __expf(lg[r][o]-m);
    const float s = __expf(lg[r][0]-m)+__expf(lg[r][1]-m)+__expf(lg[r][2]-m)+__expf(lg[r][3]-m);
    opw[(size_t)(r0+r)*4+o] = e/s;
  }

  // fused tau phase: 1024 sample logits from cols 0..1023
  {
    const int c0 = tid * 4;
    float z[4][4];
    const float4 bb = *(const float4*)(rs_b2 + c0);
#pragma unroll
    for (int r = 0; r < 4; ++r) { z[r][0]=bb.x; z[r][1]=bb.y; z[r][2]=bb.z; z[r][3]=bb.w; }
    for (int k = 0; k < HD; ++k) {
      const float4 ww = *(const float4*)(rs_w2 + (size_t)k * FF + c0);
#pragma unroll
      for (int r = 0; r < 4; ++r) {
        const float a = hl[r * HD + k];
        z[r][0] = fmaf(a, ww.x, z[r][0]);
        z[r][1] = fmaf(a, ww.y, z[r][1]);
        z[r][2] = fmaf(a, ww.z, z[r][2]);
        z[r][3] = fmaf(a, ww.w, z[r][3]);
      }
    }
#pragma unroll
    for (int r = 0; r < 4; ++r) {
      float s1 = z[r][0] + z[r][1] + z[r][2] + z[r][3];
      float s2 = z[r][0]*z[r][0] + z[r][1]*z[r][1] + z[r][2]*z[r][2] + z[r][3]*z[r][3];
#pragma unroll
      for (int d = 1; d < 64; d <<= 1) { s1 += __shfl_xor(s1, d); s2 += __shfl_xor(s2, d); }
      if (lane == 0) { wred[wave][r][0] = s1; wred[wave][r][1] = s2; }
    }
    __syncthreads();
    if (tid < 4) {
      const float s1 = wred[0][tid][0]+wred[1][tid][0]+wred[2][tid][0]+wred[3][tid][0];
      const float s2 = wred[0][tid][1]+wred[1][tid][1]+wred[2][tid][1]+wred[3][tid][1];
      const float mu  = s1 * (1.f / 1024.f);
      const float var = fmaxf(s2 * (1.f / 1024.f) - mu * mu, 0.f);
      const float sd  = sqrtf(var);
      tau[r0 + tid] = (sd > 1e-6f * (fabsf(mu) + 1e-6f)) ? (mu + 3.1f * sd) : NEG_INF;
    }
  }
}

// ---------------------------------------------------------------------------
// Kernel 2: bf16 MFMA GEMM, 128 cols x 512 rows per block.
// R9: per-wave 64x64 tile split into TWO sequential 32x64 half-tiles (rh) so
// peak live regs ~96 (acc 32 + af 8 + bfr 16 + misc) -> no spill at
// launch_bounds(256,3) (R8's (256,4) forced VGPR=64 and spilled acc: 1.15 GB
// scratch writes). B-frags in LDS; branchless clamp-poly entropy with __any
// exact correction; XCD swizzle for W2 L2 reuse.
// ---------------------------------------------------------------------------
__global__ __launch_bounds__(256, 3) void k2_sel(
    const float* __restrict__ W2, const float* __restrict__ b2,
    const float* __restrict__ hrs, const unsigned short* __restrict__ hb,
    const float* __restrict__ tau,
    int* __restrict__ gcnt, float* __restrict__ gz, int* __restrict__ gi,
    float* __restrict__ ent_part, int capr)
{
  __shared__ uint4 Blds[2][16][64];   // [col-half][ct*4+ks][lane]  32 KB
  __shared__ int   cands[BCAP];       // 4 KB
  __shared__ float tau_l[512];        // 2 KB
  __shared__ int   bcnt;
  __shared__ float entred[4];

  const int tid  = threadIdx.x;
  const int wave = tid >> 6, lane = tid & 63;
  const int n16  = lane & 15, quad = lane >> 4;
  // swizzle: XCD = bx%8; 4 consecutive in-XCD blocks share col-chunk cc
  const int xcd = blockIdx.x & 7, jj = blockIdx.x >> 3;
  const int cc  = ((jj >> 2) << 3) | xcd, rs = jj & 3;
  const int c0  = cc * 128, rbase = rs * 512;
  const int half = wave & 1, wrow0 = (wave >> 1) * 64;
  const int wcol0 = half * 64;

  if (tid == 0) bcnt = 0;
  tau_l[tid] = tau[rbase + tid];
  tau_l[tid + 256] = tau[rbase + 256 + tid];

  // stage B: fp32 W2 -> bf16 fragments in LDS (2048 uint4, 8 per thread)
  for (int p = 0; p < 8; ++p) {
    const int pid = p * 256 + tid;
    const int bh = pid >> 10;
    const int rest = pid & 1023;
    const int bct = rest >> 8, bks = (rest >> 6) & 3, bln = rest & 63;
    const int bn16 = bln & 15, bqd = bln >> 4;
    const int col = c0 + bh * 64 + bct * 16 + bn16;
    const int k0 = bks * 32 + bqd * 8;
    short8 f;
#pragma unroll
    for (int u = 0; u < 8; ++u)
      f[u] = (short)bf16_rne(W2[(size_t)(k0 + u) * FF + col]);
    Blds[bh][bct * 4 + bks][bln] = __builtin_bit_cast(uint4, f);
  }
  __syncthreads();

  float bv[4];
#pragma unroll
  for (int ct = 0; ct < 4; ++ct) bv[ct] = b2[c0 + wcol0 + ct * 16 + n16];

  float ent = 0.f;

  for (int mt = 0; mt < 4; ++mt) {
#pragma unroll
    for (int rh = 0; rh < 2; ++rh) {           // two 32-row half-tiles
      const int hrow = rbase + mt * 128 + wrow0 + rh * 32;

      f32x4 acc[2][4];
#pragma unroll
      for (int rt = 0; rt < 2; ++rt)
#pragma unroll
        for (int ct = 0; ct < 4; ++ct) acc[rt][ct] = (f32x4){0.f, 0.f, 0.f, 0.f};

#pragma unroll
      for (int ks = 0; ks < 4; ++ks) {
        short8 af[2], bfr[4];
#pragma unroll
        for (int rt = 0; rt < 2; ++rt)
          af[rt] = __builtin_bit_cast(short8,
              *(const uint4*)(hb + (size_t)(hrow + rt * 16 + n16) * HD + ks * 32 + quad * 8));
#pragma unroll
        for (int ct = 0; ct < 4; ++ct)
          bfr[ct] = __builtin_bit_cast(short8, Blds[half][ct * 4 + ks][lane]);
#pragma unroll
        for (int rt = 0; rt < 2; ++rt)
#pragma unroll
          for (int ct = 0; ct < 4; ++ct)
            acc[rt][ct] = __builtin_amdgcn_mfma_f32_16x16x32_bf16(
                af[rt], bfr[ct], acc[rt][ct], 0, 0, 0);
      }

      // branchless entropy (clamped poly) + __any-guarded filter
      float zmax = 0.f;
#pragma unroll
      for (int rt = 0; rt < 2; ++rt) {
        const int rl0 = mt * 128 + wrow0 + rh * 32 + rt * 16 + quad * 4;  // block-local
        const f32x4 tl = *(const f32x4*)&tau_l[rl0];
#pragma unroll
        for (int ct = 0; ct < 4; ++ct) {
#pragma unroll
          for (int rg = 0; rg < 4; ++rg) {
            const float z = acc[rt][ct][rg] + bv[ct];
            zmax = fmaxf(zmax, __builtin_fabsf(z));
            const float zc = fminf(fmaxf(z, -ZCLAMP), ZCLAMP);
            ent -= hpoly(zc);
            if (__any(z >= tl[rg])) {
              if (z >= tl[rg]) {
                const int q  = atomicAdd(&bcnt, 1);
                const int gm = rl0 + rg;
                if (q < BCAP) cands[q] = (gm << 7) | (wcol0 + ct * 16 + n16);
                else atomicOr(&gcnt[rbase + gm], POISON);
              }
            }
          }
        }
      }
      if (__any(zmax > ZCLAMP)) {   // rare exact correction for clamped values
#pragma unroll
        for (int rt = 0; rt < 2; ++rt)
#pragma unroll
          for (int ct = 0; ct < 4; ++ct)
#pragma unroll
            for (int rg = 0; rg < 4; ++rg) {
              const float z = acc[rt][ct][rg] + bv[ct];
              if (__builtin_fabsf(z) > ZCLAMP) {
                const float zc = fminf(fmaxf(z, -ZCLAMP), ZCLAMP);
                const float zx = fmaxf(z, -60.f);
                const float w = 1.f + __expf(-zx);
                ent += hpoly(zc) - __logf(w) * __builtin_amdgcn_rcpf(w);
              }
            }
      }
    }
  }

  __syncthreads();
  // exact fp32 recompute of candidates: one 16-lane group per candidate
  {
    const int nc = min(bcnt, BCAP);
    const int grp = tid >> 4, gl = tid & 15;
    for (int ci = grp; ci < nc; ci += 16) {
      const int pk = cands[ci];
      const int r = rbase + (pk >> 7), c = c0 + (pk & 127);
      float s = 0.f;
      const int k0 = gl * 8;
#pragma unroll
      for (int u = 0; u < 8; ++u)
        s = fmaf(hrs[(size_t)r * HD + k0 + u], W2[(size_t)(k0 + u) * FF + c], s);
#pragma unroll
      for (int d = 1; d < 16; d <<= 1) s += __shfl_xor(s, d);
      if (gl == 0) {
        const float z = s + b2[c];
        const int pos = atomicAdd(&gcnt[r], 1);
        if (pos < capr) {
          gz[(size_t)r * capr + pos] = z;
          gi[(size_t)r * capr + pos] = c;
        }
      }
    }
  }

  // entropy reduce -> one partial per block
#pragma unroll
  for (int off = 32; off >= 1; off >>= 1) ent += __shfl_down(ent, off);
  if (lane == 0) entred[wave] = ent;
  __syncthreads();
  if (tid == 0) ent_part[blockIdx.x] = entred[0] + entred[1] + entred[2] + entred[3];
}

// ---------------------------------------------------------------------------
// Kernel 3: per-row selection (R4-R8-verified). Fast path: count in [15,capr]
// AND exact-15th >= sigmoid(tau) certificate; else block-cooperative exact
// full-row scan (~never).
// ---------------------------------------------------------------------------
__global__ __launch_bounds__(256) void k3_select(
    const int* __restrict__ gcnt, const float* __restrict__ gz, const int* __restrict__ gi,
    const float* __restrict__ tau,
    const float* __restrict__ hrs, const float* __restrict__ W2, const float* __restrict__ b2,
    const float* __restrict__ tf, const float* __restrict__ opw,
    float* __restrict__ out_rt, float* __restrict__ pi_part, float* __restrict__ mag_part,
    int capr)
{
  __shared__ float csv[4][MAXCH][16];
  __shared__ int   csi[4][MAXCH][16];
  __shared__ float tv[4][TK];
  __shared__ int   ti[4][TK];
  __shared__ float s_pi[4][TK];
  __shared__ float s_mag[4][TK];
  __shared__ float red_v[256];
  __shared__ int   red_i[256];
  __shared__ float hrow[HD];
  __shared__ int   fb_w[4];
  __shared__ int   fb_n;

  const int tid  = threadIdx.x;
  const int wave = tid >> 6, lane = tid & 63;
  const int row  = blockIdx.x * 4 + wave;
  if (tid == 0) fb_n = 0;
  __syncthreads();

  const int raw = gcnt[row];
  const float tau_r = tau[row];
  int okflag = (raw >= TK && raw <= capr) ? 1 : 0;

  if (okflag) {
    const int nch = (raw + 63) >> 6;   // <= MAXCH
    for (int ch = 0; ch < nch; ++ch) {
      const int sl = ch * 64 + lane;
      float v; int ix;
      if (sl < raw) {
        const float z = gz[(size_t)row * capr + sl];
        v  = 1.f / (1.f + __expf(-z));
        ix = gi[(size_t)row * capr + sl];
      } else { v = -1.f; ix = 0x7fffffff; }
#pragma unroll
      for (int k = 2; k <= 64; k <<= 1) {
#pragma unroll
        for (int j = k >> 1; j >= 1; j >>= 1) {
          const float pv = __shfl_xor(v, j);
          const int   pj = __shfl_xor(ix, j);
          const bool up    = ((lane & k) == 0);
          const bool lower = ((lane & j) == 0);
          const bool gt = (v > pv) || (v == pv && ix < pj);
          const bool keep = (lower == up) ? gt : !gt;
          if (!keep) { v = pv; ix = pj; }
        }
      }
      if (lane < 16) { csv[wave][ch][lane] = v; csi[wave][ch][lane] = ix; }
    }
    if (lane == 0) {
      int p[MAXCH];
#pragma unroll
      for (int i = 0; i < MAXCH; ++i) p[i] = 0;
      for (int round = 0; round < TK; ++round) {
        float bvv = -2.f; int bi = 0x7fffffff; int bw = 0;
        for (int ch = 0; ch < nch; ++ch) {
          if (p[ch] < 16) {
            const float vv = csv[wave][ch][p[ch]];
            const int   ii = csi[wave][ch][p[ch]];
            if (vv > bvv || (vv == bvv && ii < bi)) { bvv = vv; bi = ii; bw = ch; }
          }
        }
        ++p[bw];
        tv[wave][round] = bvv; ti[wave][round] = bi;
      }
      const float stau = 1.f / (1.f + __expf(-tau_r));
      if (tv[wave][TK - 1] < stau) okflag = 0;   // certificate
    }
    okflag = __shfl(okflag, 0);
  }
  if (!okflag && lane == 0) { const int q = atomicAdd(&fb_n, 1); fb_w[q] = wave; }
  __syncthreads();

  const int nfb = fb_n;
  for (int f = 0; f < nfb; ++f) {
    const int w = fb_w[f];
    const int frow = blockIdx.x * 4 + w;
    for (int i = tid; i < HD; i += 256) hrow[i] = hrs[(size_t)frow * HD + i];
    __syncthreads();
    float kv[TK]; int ki[TK];
#pragma unroll
    for (int q = 0; q < TK; ++q) { kv[q] = -2.f; ki[q] = 0x7fffffff; }
    for (int u = 0; u < FF / 256; ++u) {
      const int c = u * 256 + tid;
      float z = b2[c];
      for (int k = 0; k < HD; ++k) z = fmaf(hrow[k], W2[(size_t)k * FF + c], z);
      const float s = 1.f / (1.f + __expf(-z));
      if (s > kv[TK-1] || (s == kv[TK-1] && c < ki[TK-1])) {
        float cv = s; int cc2 = c;
#pragma unroll
        for (int q = 0; q < TK; ++q) {
          const bool bet = (cv > kv[q]) || (cv == kv[q] && cc2 < ki[q]);
          const float tq = kv[q]; const int tj = ki[q];
          if (bet) { kv[q] = cv; ki[q] = cc2; cv = tq; cc2 = tj; }
        }
      }
    }
    int pi = 0;
    for (int round = 0; round < TK; ++round) {
      red_v[tid] = (pi < TK) ? kv[pi] : -2.f;
      red_i[tid] = (pi < TK) ? ki[pi] : 0x7fffffff;
      __syncthreads();
      for (int off = 128; off >= 1; off >>= 1) {
        if (tid < off) {
          const float ov = red_v[tid + off]; const int oi = red_i[tid + off];
          if (ov > red_v[tid] || (ov == red_v[tid] && oi < red_i[tid])) {
            red_v[tid] = ov; red_i[tid] = oi;
          }
        }
        __syncthreads();
      }
      const float wv = red_v[0]; const int wi = red_i[0];
      __syncthreads();
      if (pi < TK && ki[pi] == wi) ++pi;
      if (tid == 0) { tv[w][round] = wv; ti[w][round] = wi; }
    }
    __syncthreads();
  }
  __syncthreads();

  if (lane < TK) {
    const float rv = tv[wave][lane];
    const int j = ti[wave][lane], ii = j >> 8, jj = j & 255;
    const float fi = tf[(size_t)row * FD + ii];
    const float fj = tf[(size_t)row * FD + jj];
    const float* w = opw + (size_t)row * 4;
    const float ratio = fi / (fabsf(fj) + EPSF);
    const float lr    = logf(fabsf(fi) + EPSF) - logf(fabsf(fj) + EPSF);
    const float rt    = ratio * w[0] + lr * w[1] + (fi - fj) * w[2] + fi * fj * w[3];
    out_rt[(size_t)row * TK + lane] = rt;
    s_pi[wave][lane]  = rv;
    s_mag[wave][lane] = fabsf(rt);
  }
  __syncthreads();
  if (tid < TK) {
    pi_part[(size_t)blockIdx.x * TK + tid]  = s_pi[0][tid]+s_pi[1][tid]+s_pi[2][tid]+s_pi[3][tid];
    mag_part[(size_t)blockIdx.x * TK + tid] = s_mag[0][tid]+s_mag[1][tid]+s_mag[2][tid]+s_mag[3][tid];
  }
}

// ---------------------------------------------------------------------------
// Kernel 4: final reductions, 4 independent sections -> 4 blocks.
// ---------------------------------------------------------------------------
__global__ __launch_bounds__(256) void k4_final(
    const float* __restrict__ pi_part, const float* __restrict__ mag_part,
    const float* __restrict__ opw, const float* __restrict__ ent_part,
    float* __restrict__ out)
{
  __shared__ float red[256];
  const int tid = threadIdx.x;
  const int NB3 = BB / 4;          // 512
  const int base = BB * TK;        // 30720
  const int sec = blockIdx.x;

  if (sec == 0) {
    const int r = tid & 15, seg = tid >> 4;
    float s = 0.f;
    if (r < TK) for (int q = seg; q < NB3; q += 16) s += pi_part[(size_t)q * TK + r];
    red[tid] = s; __syncthreads();
    if (tid < TK) { float t = 0.f; for (int g = 0; g < 16; ++g) t += red[g*16 + tid];
      out[base + tid] = t / (float)BB; }
  } else if (sec == 1) {
    const int r = tid & 15, seg = tid >> 4;
    float s = 0.f;
    if (r < TK) for (int q = seg; q < NB3; q += 16) s += mag_part[(size_t)q * TK + r];
    red[tid] = s; __syncthreads();
    if (tid < TK) { float t = 0.f; for (int g = 0; g < 16; ++g) t += red[g*16 + tid];
      out[base + 19 + tid] = t / (float)BB; }
  } else if (sec == 2) {
    const int o = tid & 3, seg = tid >> 2;
    float s = 0.f;
    for (int q = seg; q < BB; q += 64) s += opw[(size_t)q * 4 + o];
    red[tid] = s; __syncthreads();
    if (tid < 4) { float t = 0.f; for (int g = 0; g < 64; ++g) t += red[g*4 + tid];
      out[base + 15 + tid] = t / (float)BB; }
  } else {
    float s = 0.f;
    for (int q = tid; q < 2048; q += 256) s += ent_part[q];
    red[tid] = s; __syncthreads();
    for (int off = 128; off >= 1; off >>= 1) {
      if (tid < off) red[tid] += red[tid + off];
      __syncthreads();
    }
    if (tid == 0) out[base + 34] = -red[0] / (float)BB;
  }
}

// ---------------------------------------------------------------------------
extern "C" void kernel_launch(void* const* d_in, const int* in_sizes, int n_in,
                              void* d_out, int out_size, void* d_ws, size_t ws_size,
                              hipStream_t stream) {
  (void)in_sizes; (void)n_in; (void)out_size;
  const float* x     = (const float*)d_in[0];
  const float* rs_w1 = (const float*)d_in[1];
  const float* rs_b1 = (const float*)d_in[2];
  const float* rs_w2 = (const float*)d_in[3];
  const float* rs_b2 = (const float*)d_in[4];
  const float* os_w1 = (const float*)d_in[5];
  const float* os_b1 = (const float*)d_in[6];
  const float* os_w2 = (const float*)d_in[7];
  const float* os_b2 = (const float*)d_in[8];
  const float* ft_w1 = (const float*)d_in[9];
  const float* ft_b1 = (const float*)d_in[10];
  const float* ft_w2 = (const float*)d_in[11];
  const float* ft_b2 = (const float*)d_in[12];
  float* out = (float*)d_out;

  float* ws       = (float*)d_ws;
  float* hrs      = ws;                                 // 2048*128 f32
  float* tf       = hrs + (size_t)BB * HD;              // 2048*256 f32
  float* opw      = tf + (size_t)BB * FD;               // 2048*4 f32
  float* ent_part = opw + (size_t)BB * 4;               // 2048 f32 (k2 blocks)
  float* pi_part  = ent_part + 2048;                    // 512*15 f32
  float* mag_part = pi_part + 512 * TK;                 // 512*15 f32
  float* tau      = mag_part + 512 * TK;                // 2048 f32
  unsigned short* hb = (unsigned short*)(tau + BB);     // 2048*128 bf16
  int*   gcnt     = (int*)(hb + (size_t)BB * HD);       // 2048 int
  float* gz       = (float*)(gcnt + BB);                // 2048*capr f32
  const size_t fixed = (size_t)((char*)gz - (char*)d_ws);
  int capr = 64 * MAXCH;                                // 256 target
  while (capr > 64 && fixed + (size_t)BB * capr * 8 > ws_size) capr -= 64;
  int* gi = (int*)(gz + (size_t)BB * capr);

  hipLaunchKernelGGL(k1_front, dim3(BB / 4), dim3(256), 0, stream,
                     x, rs_w1, rs_b1, rs_w2, rs_b2, os_w1, os_b1, os_w2, os_b2,
                     ft_w1, ft_b1, ft_w2, ft_b2, hrs, hb, tf, opw, tau, gcnt);
  hipLaunchKernelGGL(k2_sel, dim3(512 * 4), dim3(256), 0, stream,
                     rs_w2, rs_b2, hrs, hb, tau, gcnt, gz, gi, ent_part, capr);
  hipLaunchKernelGGL(k3_select, dim3(BB / 4), dim3(256), 0, stream,
                     gcnt, gz, gi, tau, hrs, rs_w2, rs_b2, tf, opw,
                     out, pi_part, mag_part, capr);
  hipLaunchKernelGGL(k4_final, dim3(4), dim3(256), 0, stream,
                     pi_part, mag_part, opw, ent_part, out);
}